// Round 1
// baseline (217.157 us; speedup 1.0000x reference)
//
#include <hip/hip_runtime.h>
#include <math.h>

// Problem constants
#define A_N 4
#define H_N 8
#define DK  64
#define DIN 512
#define BSZ 128
#define TT  512
// TEMP = sqrt(64) = 8 -> multiply by 0.125f

// ws layout: P [8][4][4][512] f32 (65536 floats), then qb [8][4][4] (128 floats)

__global__ __launch_bounds__(512) void pk_kernel(const float* __restrict__ Q,
                                                 const float* __restrict__ Wk,
                                                 const float* __restrict__ bk,
                                                 float* __restrict__ P,
                                                 float* __restrict__ qb) {
    const int bid = blockIdx.x;      // [0,128): (h, bg, ua)
    const int h  = bid >> 4;
    const int bg = (bid >> 2) & 3;
    const int ua = bid & 3;
    const int a_q = h >> 1;
    const int h_q = (4 * h + bg) & 7;
    const int ch_base = ua * 512 + h * 64;

    __shared__ float qv[64];
    __shared__ float red[64];
    const int tid = threadIdx.x;
    if (tid < 64) qv[tid] = Q[(a_q * H_N + h_q) * DK + tid];
    __syncthreads();

    // one s per thread (512 threads)
    const int s = tid;
    float acc = 0.f;
    #pragma unroll 8
    for (int d = 0; d < 64; ++d)
        acc += qv[d] * Wk[(size_t)(ch_base + d) * DIN + s];
    P[((h * 4 + bg) * 4 + ua) * 512 + s] = acc;

    if (tid < 64) red[tid] = qv[tid] * bk[ch_base + tid];
    __syncthreads();
    if (tid == 0) {
        float sum = 0.f;
        for (int d = 0; d < 64; ++d) sum += red[d];
        qb[(h * 4 + bg) * 4 + ua] = sum;
    }
}

__global__ __launch_bounds__(256) void attn_kernel(const float* __restrict__ v,
                                                   const float* __restrict__ P,
                                                   const float* __restrict__ qb,
                                                   float* __restrict__ out,   // [4096][64]
                                                   float* __restrict__ attn)  // [4096][512]
{
    const int x = blockIdx.x;         // row index
    const int h = x >> 9;
    const int b = (x >> 2) & 127;
    const int j = x & 3;
    const int bg = b >> 5;
    const int tid = threadIdx.x;

    __shared__ float p_lds[4 * 516];   // padded rows: 516 % 32 = 4 -> ua spreads banks
    __shared__ float sc[512];          // attn weights for step 3
    __shared__ float redm[4];
    __shared__ float reds[4];
    __shared__ float redo[256];

    // stage P[h][bg][*][*] (2048 floats, coalesced)
    const float* Pb = P + (size_t)((h * 4 + bg) * 4) * 512;
    for (int i = tid; i < 2048; i += 256) {
        p_lds[(i >> 9) * 516 + (i & 511)] = Pb[i];
    }
    const int ua = tid & 3;
    const float qbv = qb[(h * 4 + bg) * 4 + ua];
    __syncthreads();

    // ---- scores for u1 = tid, u2 = tid + 256 (same ua) ----
    float lg[2];
    #pragma unroll
    for (int p2 = 0; p2 < 2; ++p2) {
        const int u = tid + p2 * 256;
        const int trow = u >> 2;                    // [0,128)
        const float4* vrow = (const float4*)(v + ((size_t)b * TT + (j * 128 + trow)) * DIN);
        const float4* prow = (const float4*)(p_lds + ua * 516);
        float acc = 0.f;
        #pragma unroll 4
        for (int s4 = 0; s4 < 128; ++s4) {
            const float4 pv = prow[s4];
            const float4 vv = vrow[s4];
            acc += pv.x * vv.x + pv.y * vv.y + pv.z * vv.z + pv.w * vv.w;
        }
        lg[p2] = (acc + qbv) * 0.125f;
    }

    // ---- softmax over 512 values in block ----
    float m = fmaxf(lg[0], lg[1]);
    #pragma unroll
    for (int off = 32; off > 0; off >>= 1)
        m = fmaxf(m, __shfl_xor(m, off));
    if ((tid & 63) == 0) redm[tid >> 6] = m;
    __syncthreads();
    const float M = fmaxf(fmaxf(redm[0], redm[1]), fmaxf(redm[2], redm[3]));

    const float e0 = expf(lg[0] - M);
    const float e1 = expf(lg[1] - M);
    float ssum = e0 + e1;
    #pragma unroll
    for (int off = 32; off > 0; off >>= 1)
        ssum += __shfl_xor(ssum, off);
    if ((tid & 63) == 0) reds[tid >> 6] = ssum;
    __syncthreads();
    const float S = reds[0] + reds[1] + reds[2] + reds[3];
    const float inv = 1.f / S;

    const float a0 = e0 * inv;
    const float a1 = e1 * inv;
    attn[(size_t)x * 512 + tid]       = a0;
    attn[(size_t)x * 512 + tid + 256] = a1;
    sc[tid]       = a0;
    sc[tid + 256] = a1;
    __syncthreads();

    // ---- out[cc] = sum_u attn[u] * v[b, u, h*64+cc] ----
    const int cc = tid & 63;
    const int part = tid >> 6;
    const float* vcol = v + (size_t)b * TT * DIN + h * 64 + cc;
    float acc = 0.f;
    const int u0 = part * 128;
    #pragma unroll 8
    for (int u = u0; u < u0 + 128; ++u)
        acc += sc[u] * vcol[(size_t)u * DIN];
    redo[tid] = acc;
    __syncthreads();
    if (part == 0) {
        const float sum = redo[cc] + redo[64 + cc] + redo[128 + cc] + redo[192 + cc];
        out[(size_t)x * 64 + cc] = sum;
    }
}

extern "C" void kernel_launch(void* const* d_in, const int* in_sizes, int n_in,
                              void* d_out, int out_size, void* d_ws, size_t ws_size,
                              hipStream_t stream) {
    const float* v  = (const float*)d_in[0];
    const float* Q  = (const float*)d_in[1];
    const float* Wk = (const float*)d_in[2];
    const float* bk = (const float*)d_in[3];

    float* out  = (float*)d_out;               // 4096*64
    float* attn = out + 4096 * 64;             // 4096*512

    float* P  = (float*)d_ws;                  // 65536 floats
    float* qb = P + 65536;                     // 128 floats

    pk_kernel<<<128, 512, 0, stream>>>(Q, Wk, bk, P, qb);
    attn_kernel<<<4096, 256, 0, stream>>>(v, P, qb, out, attn);
}

// Round 2
// 72.419 us; speedup vs baseline: 2.9986x; 2.9986x over previous
//
#include <hip/hip_runtime.h>
#include <math.h>

#define DIN 512
#define TT  512
#define BSZ 128

// ws layout: Pg[4][512][32] f32 (65536), qb[4][32] (128). Both pre-scaled by 0.125.

__global__ __launch_bounds__(512) void pk_kernel(const float* __restrict__ Q,
                                                 const float* __restrict__ Wk,
                                                 const float* __restrict__ bk,
                                                 float* __restrict__ Pg,
                                                 float* __restrict__ qb) {
    const int bid = blockIdx.x;   // [0,128) = bg*32 + p
    const int bg = bid >> 5;
    const int p  = bid & 31;
    const int h  = p >> 2;
    const int ua = p & 3;
    const int a_q = h >> 1;
    const int h_q = (4 * h + bg) & 7;
    const int ch_base = ua * 512 + h * 64;

    __shared__ float qv[64];
    const int tid = threadIdx.x;
    if (tid < 64) qv[tid] = Q[(a_q * 8 + h_q) * 64 + tid];
    __syncthreads();

    const int s = tid;            // 512 threads, one s each
    float acc = 0.f;
    #pragma unroll 8
    for (int d = 0; d < 64; ++d)
        acc += qv[d] * Wk[(size_t)(ch_base + d) * DIN + s];
    Pg[((size_t)bg * 512 + s) * 32 + p] = acc * 0.125f;

    if (tid == 0) {
        float sum = 0.f;
        for (int d = 0; d < 64; ++d) sum += qv[d] * bk[ch_base + d];
        qb[bg * 32 + p] = sum * 0.125f;
    }
}

// One block per (b, j). GEMM scores[128 rows][32 pvecs] = V[128x512] * P^T, then
// per-h softmax via half-wave shuffle (thread (rg,pg) holds rows rg*4..+3 of h=pg).
__global__ __launch_bounds__(256) void score_kernel(const float* __restrict__ v,
                                                    const float* __restrict__ Pg,
                                                    const float* __restrict__ qb,
                                                    float* __restrict__ attn) {
    const int bid = blockIdx.x;   // b*4 + j
    const int b = bid >> 2;
    const int j = bid & 3;
    const int bg = b >> 5;
    const int tid = threadIdx.x;
    const int rg = tid & 31;      // row group: rows rg*4..rg*4+3
    const int pg = tid >> 5;      // pvec group = h: pvecs pg*4..pg*4+3

    __shared__ float Vt[32][128];     // [k within tile][row], transposed
    __shared__ float Pt[32][36];      // [k within tile][pvec], padded

    const float* vbase = v + ((size_t)b * TT + j * 128) * DIN;
    const float* pbase = Pg + (size_t)bg * 512 * 32;

    float acc[4][4];
    #pragma unroll
    for (int i = 0; i < 4; ++i)
        #pragma unroll
        for (int jj = 0; jj < 4; ++jj) acc[i][jj] = 0.f;

    const int r_st  = tid & 127;      // staging row
    const int khalf = tid >> 7;       // staging k half

    for (int kt = 0; kt < 16; ++kt) {
        const int k0 = kt * 32;
        __syncthreads();
        // ---- stage V tile transposed: Vt[kk][r] = v[row r][k0+kk] ----
        #pragma unroll
        for (int it = 0; it < 4; ++it) {
            const int kk = khalf * 16 + it * 4;
            const float4 t4 = *(const float4*)(vbase + (size_t)r_st * DIN + k0 + kk);
            Vt[kk + 0][r_st] = t4.x;
            Vt[kk + 1][r_st] = t4.y;
            Vt[kk + 2][r_st] = t4.z;
            Vt[kk + 3][r_st] = t4.w;
        }
        // ---- stage P tile (already transposed in global): Pt[kk][p] ----
        {
            const int kk = tid >> 3;
            const int p4 = (tid & 7) * 4;
            const float4 t4 = *(const float4*)(pbase + (size_t)(k0 + kk) * 32 + p4);
            *(float4*)&Pt[kk][p4] = t4;
        }
        __syncthreads();
        // ---- 16 FMA per 2 LDS vector reads ----
        #pragma unroll
        for (int k = 0; k < 32; ++k) {
            const float4 v4 = *(const float4*)&Vt[k][rg * 4];
            const float4 p4 = *(const float4*)&Pt[k][pg * 4];
            acc[0][0] += v4.x * p4.x; acc[0][1] += v4.x * p4.y; acc[0][2] += v4.x * p4.z; acc[0][3] += v4.x * p4.w;
            acc[1][0] += v4.y * p4.x; acc[1][1] += v4.y * p4.y; acc[1][2] += v4.y * p4.z; acc[1][3] += v4.y * p4.w;
            acc[2][0] += v4.z * p4.x; acc[2][1] += v4.z * p4.y; acc[2][2] += v4.z * p4.z; acc[2][3] += v4.z * p4.w;
            acc[3][0] += v4.w * p4.x; acc[3][1] += v4.w * p4.y; acc[3][2] += v4.w * p4.z; acc[3][3] += v4.w * p4.w;
        }
    }

    // logits = acc + qb (both already scaled by 0.125)
    const float qb0 = qb[bg * 32 + pg * 4 + 0];
    const float qb1 = qb[bg * 32 + pg * 4 + 1];
    const float qb2 = qb[bg * 32 + pg * 4 + 2];
    const float qb3 = qb[bg * 32 + pg * 4 + 3];
    float lg[4][4];
    #pragma unroll
    for (int i = 0; i < 4; ++i) {
        lg[i][0] = acc[i][0] + qb0;
        lg[i][1] = acc[i][1] + qb1;
        lg[i][2] = acc[i][2] + qb2;
        lg[i][3] = acc[i][3] + qb3;
    }

    // softmax over the 32 lanes sharing pg (half-wave) x 16 values each
    float m = lg[0][0];
    #pragma unroll
    for (int i = 0; i < 4; ++i)
        #pragma unroll
        for (int jj = 0; jj < 4; ++jj) m = fmaxf(m, lg[i][jj]);
    #pragma unroll
    for (int off = 16; off > 0; off >>= 1) m = fmaxf(m, __shfl_xor(m, off));

    float e[4][4];
    float ssum = 0.f;
    #pragma unroll
    for (int i = 0; i < 4; ++i)
        #pragma unroll
        for (int jj = 0; jj < 4; ++jj) { e[i][jj] = expf(lg[i][jj] - m); ssum += e[i][jj]; }
    #pragma unroll
    for (int off = 16; off > 0; off >>= 1) ssum += __shfl_xor(ssum, off);
    const float inv = 1.f / ssum;

    // write attn[x][u]: x = pg*512 + b*4 + j, u = rg*16 + i*4 + ua  (contiguous 16)
    float* abase = attn + ((size_t)(pg * 512 + b * 4 + j)) * 512 + rg * 16;
    #pragma unroll
    for (int i = 0; i < 4; ++i) {
        float4 w;
        w.x = e[i][0] * inv; w.y = e[i][1] * inv; w.z = e[i][2] * inv; w.w = e[i][3] * inv;
        *(float4*)(abase + i * 4) = w;
    }
}

// One block per (b, h): out[x=(h,b,j)][c] = sum_u attn[x][u] * v[b,u,h*64+c]
__global__ __launch_bounds__(256) void pv_kernel(const float* __restrict__ v,
                                                 const float* __restrict__ attn,
                                                 float* __restrict__ out) {
    const int bid = blockIdx.x;   // b*8 + h
    const int b = bid >> 3;
    const int h = bid & 7;
    const int tid = threadIdx.x;

    __shared__ float at[4][512];
    __shared__ float red[16][4][68];

    {   // stage attn rows for 4 j values (8 KB, coalesced)
        const int j  = tid >> 6;
        const int u8 = (tid & 63) * 8;
        const float* src = attn + ((size_t)(h * 512 + b * 4 + j)) * 512 + u8;
        *(float4*)&at[j][u8]     = *(const float4*)(src);
        *(float4*)&at[j][u8 + 4] = *(const float4*)(src + 4);
    }
    __syncthreads();

    const int c4 = (tid & 15) * 4;   // 4 channels per thread
    const int rr = tid >> 4;         // row phase [0,16)
    const float* vb = v + (size_t)b * TT * DIN + h * 64 + c4;

    float acc[4][4];                 // [j][ci]
    #pragma unroll
    for (int jj = 0; jj < 4; ++jj)
        #pragma unroll
        for (int ci = 0; ci < 4; ++ci) acc[jj][ci] = 0.f;

    for (int it = 0; it < 32; ++it) {
        const int u = it * 16 + rr;
        const float4 v4 = *(const float4*)(vb + (size_t)u * DIN);
        #pragma unroll
        for (int jj = 0; jj < 4; ++jj) {
            const float a = at[jj][u];
            acc[jj][0] += a * v4.x;
            acc[jj][1] += a * v4.y;
            acc[jj][2] += a * v4.z;
            acc[jj][3] += a * v4.w;
        }
    }

    #pragma unroll
    for (int jj = 0; jj < 4; ++jj)
        #pragma unroll
        for (int ci = 0; ci < 4; ++ci) red[rr][jj][c4 + ci] = acc[jj][ci];
    __syncthreads();

    const int jo = tid >> 6;
    const int c  = tid & 63;
    float s = 0.f;
    #pragma unroll
    for (int r2 = 0; r2 < 16; ++r2) s += red[r2][jo][c];
    out[((size_t)(h * 512 + b * 4 + jo)) * 64 + c] = s;
}

extern "C" void kernel_launch(void* const* d_in, const int* in_sizes, int n_in,
                              void* d_out, int out_size, void* d_ws, size_t ws_size,
                              hipStream_t stream) {
    const float* v  = (const float*)d_in[0];
    const float* Q  = (const float*)d_in[1];
    const float* Wk = (const float*)d_in[2];
    const float* bk = (const float*)d_in[3];

    float* out  = (float*)d_out;               // 4096*64
    float* attn = out + 4096 * 64;             // 4096*512

    float* Pg = (float*)d_ws;                  // 4*512*32
    float* qb = Pg + 4 * 512 * 32;             // 4*32

    pk_kernel<<<128, 512, 0, stream>>>(Q, Wk, bk, Pg, qb);
    score_kernel<<<512, 256, 0, stream>>>(v, Pg, qb, attn);
    pv_kernel<<<1024, 256, 0, stream>>>(v, attn, out);
}

// Round 3
// 71.872 us; speedup vs baseline: 3.0214x; 1.0076x over previous
//
#include <hip/hip_runtime.h>
#include <math.h>

#define DIN 512
#define TT  512
#define BSZ 128

// ws layout: Pg[4][512][32] f32 (65536), qb[4][32] (128). Both pre-scaled by 0.125.

__global__ __launch_bounds__(512) void pk_kernel(const float* __restrict__ Q,
                                                 const float* __restrict__ Wk,
                                                 const float* __restrict__ bk,
                                                 float* __restrict__ Pg,
                                                 float* __restrict__ qb) {
    const int bid = blockIdx.x;   // [0,128) = bg*32 + p
    const int bg = bid >> 5;
    const int p  = bid & 31;
    const int h  = p >> 2;
    const int ua = p & 3;
    const int a_q = h >> 1;
    const int h_q = (4 * h + bg) & 7;
    const int ch_base = ua * 512 + h * 64;

    __shared__ float qv[64];
    const int tid = threadIdx.x;
    if (tid < 64) qv[tid] = Q[(a_q * 8 + h_q) * 64 + tid];
    __syncthreads();

    const int s = tid;            // 512 threads, one s each
    float acc = 0.f;
    #pragma unroll 8
    for (int d = 0; d < 64; ++d)
        acc += qv[d] * Wk[(size_t)(ch_base + d) * DIN + s];
    Pg[((size_t)bg * 512 + s) * 32 + p] = acc * 0.125f;

    if (tid == 0) {
        float sum = 0.f;
        for (int d = 0; d < 64; ++d) sum += qv[d] * bk[ch_base + d];
        qb[bg * 32 + p] = sum * 0.125f;
    }
}

// One block per (b, j). GEMM scores[128 rows][32 pvecs] = V[128x512] * P^T with
// register-double-buffered staging; per-h softmax via half-wave shuffle.
__global__ __launch_bounds__(256) void score_kernel(const float* __restrict__ v,
                                                    const float* __restrict__ Pg,
                                                    const float* __restrict__ qb,
                                                    float* __restrict__ attn) {
    const int bid = blockIdx.x;   // b*4 + j
    const int b = bid >> 2;
    const int j = bid & 3;
    const int bg = b >> 5;
    const int tid = threadIdx.x;
    const int rg = tid & 31;      // row group: rows rg*4..rg*4+3
    const int pg = tid >> 5;      // pvec group = h: pvecs pg*4..pg*4+3

    __shared__ float Vt[32][128];     // [k within tile][row], transposed
    __shared__ float Pt[32][36];      // [k within tile][pvec], padded

    const float* vbase = v + ((size_t)b * TT + j * 128) * DIN;
    const float* pbase = Pg + (size_t)bg * 512 * 32;

    float acc[4][4];
    #pragma unroll
    for (int i = 0; i < 4; ++i)
        #pragma unroll
        for (int jj = 0; jj < 4; ++jj) acc[i][jj] = 0.f;

    const int r_st   = tid & 127;       // staging row
    const int khalf  = tid >> 7;        // staging k half
    const int kk_p   = tid >> 3;        // P staging k
    const int p4_p   = (tid & 7) * 4;   // P staging pvec

    const float* vsrc = vbase + (size_t)r_st * DIN + khalf * 16;

    // prologue: prefetch tile 0 into registers
    float4 vreg[4];
    float4 preg;
    #pragma unroll
    for (int it = 0; it < 4; ++it) vreg[it] = *(const float4*)(vsrc + it * 4);
    preg = *(const float4*)(pbase + (size_t)kk_p * 32 + p4_p);

    for (int kt = 0; kt < 16; ++kt) {
        // ---- write staged registers to LDS ----
        #pragma unroll
        for (int it = 0; it < 4; ++it) {
            const int kk = khalf * 16 + it * 4;
            Vt[kk + 0][r_st] = vreg[it].x;
            Vt[kk + 1][r_st] = vreg[it].y;
            Vt[kk + 2][r_st] = vreg[it].z;
            Vt[kk + 3][r_st] = vreg[it].w;
        }
        *(float4*)&Pt[kk_p][p4_p] = preg;
        __syncthreads();

        // ---- issue next tile's global loads (latency hides under compute) ----
        if (kt < 15) {
            const int k0n = (kt + 1) * 32;
            #pragma unroll
            for (int it = 0; it < 4; ++it)
                vreg[it] = *(const float4*)(vsrc + k0n + it * 4);
            preg = *(const float4*)(pbase + (size_t)(k0n + kk_p) * 32 + p4_p);
        }

        // ---- 16 FMA per 2 LDS vector reads ----
        #pragma unroll
        for (int k = 0; k < 32; ++k) {
            const float4 v4 = *(const float4*)&Vt[k][rg * 4];
            const float4 p4 = *(const float4*)&Pt[k][pg * 4];
            acc[0][0] += v4.x * p4.x; acc[0][1] += v4.x * p4.y; acc[0][2] += v4.x * p4.z; acc[0][3] += v4.x * p4.w;
            acc[1][0] += v4.y * p4.x; acc[1][1] += v4.y * p4.y; acc[1][2] += v4.y * p4.z; acc[1][3] += v4.y * p4.w;
            acc[2][0] += v4.z * p4.x; acc[2][1] += v4.z * p4.y; acc[2][2] += v4.z * p4.z; acc[2][3] += v4.z * p4.w;
            acc[3][0] += v4.w * p4.x; acc[3][1] += v4.w * p4.y; acc[3][2] += v4.w * p4.z; acc[3][3] += v4.w * p4.w;
        }
        __syncthreads();
    }

    // logits = acc + qb (both already scaled by 0.125)
    const float qb0 = qb[bg * 32 + pg * 4 + 0];
    const float qb1 = qb[bg * 32 + pg * 4 + 1];
    const float qb2 = qb[bg * 32 + pg * 4 + 2];
    const float qb3 = qb[bg * 32 + pg * 4 + 3];
    float lg[4][4];
    #pragma unroll
    for (int i = 0; i < 4; ++i) {
        lg[i][0] = acc[i][0] + qb0;
        lg[i][1] = acc[i][1] + qb1;
        lg[i][2] = acc[i][2] + qb2;
        lg[i][3] = acc[i][3] + qb3;
    }

    // softmax over the 32 lanes sharing pg (half-wave) x 16 values each
    float m = lg[0][0];
    #pragma unroll
    for (int i = 0; i < 4; ++i)
        #pragma unroll
        for (int jj = 0; jj < 4; ++jj) m = fmaxf(m, lg[i][jj]);
    #pragma unroll
    for (int off = 16; off > 0; off >>= 1) m = fmaxf(m, __shfl_xor(m, off));

    float e[4][4];
    float ssum = 0.f;
    #pragma unroll
    for (int i = 0; i < 4; ++i)
        #pragma unroll
        for (int jj = 0; jj < 4; ++jj) { e[i][jj] = expf(lg[i][jj] - m); ssum += e[i][jj]; }
    #pragma unroll
    for (int off = 16; off > 0; off >>= 1) ssum += __shfl_xor(ssum, off);
    const float inv = 1.f / ssum;

    // write attn[x][u]: x = pg*512 + b*4 + j, u = rg*16 + i*4 + ua  (contiguous 16)
    float* abase = attn + ((size_t)(pg * 512 + b * 4 + j)) * 512 + rg * 16;
    #pragma unroll
    for (int i = 0; i < 4; ++i) {
        float4 w;
        w.x = e[i][0] * inv; w.y = e[i][1] * inv; w.z = e[i][2] * inv; w.w = e[i][3] * inv;
        *(float4*)(abase + i * 4) = w;
    }
}

// One block per (b, h): out[x=(h,b,j)][c] = sum_u attn[x][u] * v[b,u,h*64+c]
// 8 channels x 4 j per thread: 32 FMA per (2 x float4 global + 4 broadcast ds_b32)
__global__ __launch_bounds__(256) void pv_kernel(const float* __restrict__ v,
                                                 const float* __restrict__ attn,
                                                 float* __restrict__ out) {
    const int bid = blockIdx.x;   // b*8 + h
    const int b = bid >> 3;
    const int h = bid & 7;
    const int tid = threadIdx.x;

    __shared__ float at[4][512];
    __shared__ float red[32][4][68];   // [up][j][c], padded row

    {   // stage attn rows for 4 j values (8 KB, coalesced)
        const int j  = tid >> 6;
        const int u8 = (tid & 63) * 8;
        const float* src = attn + ((size_t)(h * 512 + b * 4 + j)) * 512 + u8;
        *(float4*)&at[j][u8]     = *(const float4*)(src);
        *(float4*)&at[j][u8 + 4] = *(const float4*)(src + 4);
    }
    __syncthreads();

    const int cg = tid & 7;          // channel octet: c8 = cg*8
    const int up = tid >> 3;         // u phase [0,32)
    const int c8 = cg * 8;
    const float* vb = v + (size_t)b * TT * DIN + h * 64 + c8;

    float acc[4][8];
    #pragma unroll
    for (int jj = 0; jj < 4; ++jj)
        #pragma unroll
        for (int ci = 0; ci < 8; ++ci) acc[jj][ci] = 0.f;

    // prologue prefetch u = up
    const float* pcur = vb + (size_t)up * DIN;
    float4 r0 = *(const float4*)(pcur);
    float4 r1 = *(const float4*)(pcur + 4);

    for (int it = 0; it < 16; ++it) {
        const int u = it * 32 + up;
        const float4 c0 = r0;
        const float4 c1 = r1;
        if (it < 15) {
            const float* pn = vb + (size_t)(u + 32) * DIN;
            r0 = *(const float4*)(pn);
            r1 = *(const float4*)(pn + 4);
        }
        const float a0 = at[0][u];
        const float a1 = at[1][u];
        const float a2 = at[2][u];
        const float a3 = at[3][u];
        acc[0][0] += a0 * c0.x; acc[0][1] += a0 * c0.y; acc[0][2] += a0 * c0.z; acc[0][3] += a0 * c0.w;
        acc[0][4] += a0 * c1.x; acc[0][5] += a0 * c1.y; acc[0][6] += a0 * c1.z; acc[0][7] += a0 * c1.w;
        acc[1][0] += a1 * c0.x; acc[1][1] += a1 * c0.y; acc[1][2] += a1 * c0.z; acc[1][3] += a1 * c0.w;
        acc[1][4] += a1 * c1.x; acc[1][5] += a1 * c1.y; acc[1][6] += a1 * c1.z; acc[1][7] += a1 * c1.w;
        acc[2][0] += a2 * c0.x; acc[2][1] += a2 * c0.y; acc[2][2] += a2 * c0.z; acc[2][3] += a2 * c0.w;
        acc[2][4] += a2 * c1.x; acc[2][5] += a2 * c1.y; acc[2][6] += a2 * c1.z; acc[2][7] += a2 * c1.w;
        acc[3][0] += a3 * c0.x; acc[3][1] += a3 * c0.y; acc[3][2] += a3 * c0.z; acc[3][3] += a3 * c0.w;
        acc[3][4] += a3 * c1.x; acc[3][5] += a3 * c1.y; acc[3][6] += a3 * c1.z; acc[3][7] += a3 * c1.w;
    }

    #pragma unroll
    for (int jj = 0; jj < 4; ++jj) {
        float4 w0, w1;
        w0.x = acc[jj][0]; w0.y = acc[jj][1]; w0.z = acc[jj][2]; w0.w = acc[jj][3];
        w1.x = acc[jj][4]; w1.y = acc[jj][5]; w1.z = acc[jj][6]; w1.w = acc[jj][7];
        *(float4*)&red[up][jj][c8]     = w0;
        *(float4*)&red[up][jj][c8 + 4] = w1;
    }
    __syncthreads();

    const int jo = tid >> 6;
    const int c  = tid & 63;
    float s = 0.f;
    #pragma unroll
    for (int r2 = 0; r2 < 32; ++r2) s += red[r2][jo][c];
    out[((size_t)(h * 512 + b * 4 + jo)) * 64 + c] = s;
}

extern "C" void kernel_launch(void* const* d_in, const int* in_sizes, int n_in,
                              void* d_out, int out_size, void* d_ws, size_t ws_size,
                              hipStream_t stream) {
    const float* v  = (const float*)d_in[0];
    const float* Q  = (const float*)d_in[1];
    const float* Wk = (const float*)d_in[2];
    const float* bk = (const float*)d_in[3];

    float* out  = (float*)d_out;               // 4096*64
    float* attn = out + 4096 * 64;             // 4096*512

    float* Pg = (float*)d_ws;                  // 4*512*32
    float* qb = Pg + 4 * 512 * 32;             // 4*32

    pk_kernel<<<128, 512, 0, stream>>>(Q, Wk, bk, Pg, qb);
    score_kernel<<<512, 256, 0, stream>>>(v, Pg, qb, attn);
    pv_kernel<<<1024, 256, 0, stream>>>(v, attn, out);
}

// Round 4
// 56.483 us; speedup vs baseline: 3.8446x; 1.2724x over previous
//
#include <hip/hip_runtime.h>
#include <hip/hip_bf16.h>
#include <math.h>

#define DIN 512
#define TT  512
#define BSZ 128

using bf16x8 = __attribute__((ext_vector_type(8))) short;
using f32x4  = __attribute__((ext_vector_type(4))) float;

static __device__ __forceinline__ unsigned short f2bf(float x) {
    __hip_bfloat16 h = __float2bfloat16(x);
    return *reinterpret_cast<unsigned short*>(&h);
}
static __device__ __forceinline__ unsigned int pack2(float a, float b) {
    return (unsigned int)f2bf(a) | ((unsigned int)f2bf(b) << 16);
}

// ws layout: Pgb bf16 [4 bg][32 p][512 s] (65536 ushort = 128 KB), then qb f32 [128].
// Both pre-scaled by 0.125 (temperature).

__global__ __launch_bounds__(512) void pk_kernel(const float* __restrict__ Q,
                                                 const float* __restrict__ Wk,
                                                 const float* __restrict__ bk,
                                                 unsigned short* __restrict__ Pgb,
                                                 float* __restrict__ qb) {
    const int bid = blockIdx.x;   // [0,128) = bg*32 + p
    const int bg = bid >> 5;
    const int p  = bid & 31;
    const int h  = p >> 2;
    const int ua = p & 3;
    const int a_q = h >> 1;
    const int h_q = (4 * h + bg) & 7;
    const int ch_base = ua * 512 + h * 64;

    __shared__ float qv[64];
    const int tid = threadIdx.x;
    if (tid < 64) qv[tid] = Q[(a_q * 8 + h_q) * 64 + tid];
    __syncthreads();

    const int s = tid;            // 512 threads, one s each
    float acc = 0.f;
    #pragma unroll 8
    for (int d = 0; d < 64; ++d)
        acc += qv[d] * Wk[(size_t)(ch_base + d) * DIN + s];
    Pgb[(size_t)(bg * 32 + p) * 512 + s] = f2bf(acc * 0.125f);

    if (tid == 0) {
        float sum = 0.f;
        for (int d = 0; d < 64; ++d) sum += qv[d] * bk[ch_base + d];
        qb[bg * 32 + p] = sum * 0.125f;
    }
}

// One block per (b, j). scores[128 trow][32 p] = V[128x512] @ P^T via bf16 MFMA.
// 4 waves x (2 M-tiles x 2 N-tiles) of 16x16, K-steps of 32.
__global__ __launch_bounds__(256) void score_kernel(const float* __restrict__ v,
                                                    const unsigned short* __restrict__ Pgb,
                                                    const float* __restrict__ qb,
                                                    float* __restrict__ attn) {
    const int bid = blockIdx.x;   // b*4 + j
    const int b = bid >> 2;
    const int j = bid & 3;
    const int bg = b >> 5;
    const int tid = threadIdx.x;
    const int lane = tid & 63;
    const int w = tid >> 6;       // wave id: M rows w*32..w*32+31

    // LDS: V tile [128 rows][32 k] bf16, row stride 80 B (pad -> conflict-free-at-floor)
    //      P full  [32 p][512 k] bf16, row stride 1040 B
    __shared__ char VtB[128 * 80];          // 10240 B
    __shared__ char PtB[32 * 1040];         // 33280 B
    __shared__ float red2[4][2][4][2];      // [wave][nt][hsub][m,s]

    const float* vbase = v + ((size_t)b * TT + j * 128) * DIN;

    // ---- stage full P (bf16) once: 32 KB ----
    {
        const int p  = tid >> 3;          // [0,32)
        const int sg = tid & 7;           // 64 k (128 B) each
        const uint4* src = (const uint4*)(Pgb + ((size_t)(bg * 32 + p) * 512)) + sg * 8;
        uint4* dst = (uint4*)(PtB + p * 1040 + sg * 128);
        #pragma unroll
        for (int q = 0; q < 8; ++q) dst[q] = src[q];
    }

    const float qv0 = qb[bg * 32 + (lane & 15)];
    const float qv1 = qb[bg * 32 + 16 + (lane & 15)];

    f32x4 acc[2][2];
    #pragma unroll
    for (int i = 0; i < 2; ++i)
        #pragma unroll
        for (int n = 0; n < 2; ++n)
            #pragma unroll
            for (int r = 0; r < 4; ++r) acc[i][n][r] = 0.f;

    // staging assignment: thread = row*2 + half (16 k-values = 64 B f32 each)
    const int srow  = tid >> 1;
    const int shalf = tid & 1;
    const float* vsrc = vbase + (size_t)srow * DIN + shalf * 16;
    char* vdst = VtB + srow * 80 + shalf * 32;

    // A/B frag read offsets
    const int akb = (lane >> 4) * 16;                 // k-chunk byte offset
    const char* aptr = VtB + (w * 32 + (lane & 15)) * 80 + akb;
    const char* bptr0 = PtB + ((lane & 15)) * 1040 + akb;
    const char* bptr1 = PtB + (16 + (lane & 15)) * 1040 + akb;

    // prologue: prefetch k-step 0
    float4 vr[4];
    #pragma unroll
    for (int q = 0; q < 4; ++q) vr[q] = *(const float4*)(vsrc + q * 4);

    for (int kt = 0; kt < 16; ++kt) {
        // pack prefetched f32 -> bf16 and write V tile
        uint4 lo, hi;
        lo.x = pack2(vr[0].x, vr[0].y); lo.y = pack2(vr[0].z, vr[0].w);
        lo.z = pack2(vr[1].x, vr[1].y); lo.w = pack2(vr[1].z, vr[1].w);
        hi.x = pack2(vr[2].x, vr[2].y); hi.y = pack2(vr[2].z, vr[2].w);
        hi.z = pack2(vr[3].x, vr[3].y); hi.w = pack2(vr[3].z, vr[3].w);
        *(uint4*)(vdst)      = lo;
        *(uint4*)(vdst + 16) = hi;
        __syncthreads();

        // prefetch next k-step while MFMAs run
        if (kt < 15) {
            const float* vn = vsrc + (kt + 1) * 32;
            #pragma unroll
            for (int q = 0; q < 4; ++q) vr[q] = *(const float4*)(vn + q * 4);
        }

        const int ksb = kt * 64;   // 32 k * 2 B
        bf16x8 a0 = *(const bf16x8*)(aptr);
        bf16x8 a1 = *(const bf16x8*)(aptr + 16 * 80);
        bf16x8 b0 = *(const bf16x8*)(bptr0 + ksb);
        bf16x8 b1 = *(const bf16x8*)(bptr1 + ksb);
        acc[0][0] = __builtin_amdgcn_mfma_f32_16x16x32_bf16(a0, b0, acc[0][0], 0, 0, 0);
        acc[0][1] = __builtin_amdgcn_mfma_f32_16x16x32_bf16(a0, b1, acc[0][1], 0, 0, 0);
        acc[1][0] = __builtin_amdgcn_mfma_f32_16x16x32_bf16(a1, b0, acc[1][0], 0, 0, 0);
        acc[1][1] = __builtin_amdgcn_mfma_f32_16x16x32_bf16(a1, b1, acc[1][1], 0, 0, 0);
        __syncthreads();
    }

    // ---- logits + per-h softmax ----
    // value acc[i][nt][rr] = score[trow = w*32+i*16+(lane>>4)*4+rr][p = nt*16+(lane&15)]
    float lg[2][8];
    #pragma unroll
    for (int i = 0; i < 2; ++i)
        #pragma unroll
        for (int r = 0; r < 4; ++r) {
            lg[0][i * 4 + r] = acc[i][0][r] + qv0;
            lg[1][i * 4 + r] = acc[i][1][r] + qv1;
        }

    const int hsub = (lane >> 2) & 3;
    float mw[2], sw[2], ev[2][8];
    #pragma unroll
    for (int nt = 0; nt < 2; ++nt) {
        float m = lg[nt][0];
        #pragma unroll
        for (int q = 1; q < 8; ++q) m = fmaxf(m, lg[nt][q]);
        m = fmaxf(m, __shfl_xor(m, 1));
        m = fmaxf(m, __shfl_xor(m, 2));
        m = fmaxf(m, __shfl_xor(m, 16));
        m = fmaxf(m, __shfl_xor(m, 32));
        float s = 0.f;
        #pragma unroll
        for (int q = 0; q < 8; ++q) { ev[nt][q] = __expf(lg[nt][q] - m); s += ev[nt][q]; }
        s += __shfl_xor(s, 1);
        s += __shfl_xor(s, 2);
        s += __shfl_xor(s, 16);
        s += __shfl_xor(s, 32);
        mw[nt] = m; sw[nt] = s;
    }
    if ((lane & 0x33) == 0) {   // lanes 0,4,8,12: one per hsub
        #pragma unroll
        for (int nt = 0; nt < 2; ++nt) {
            red2[w][nt][hsub][0] = mw[nt];
            red2[w][nt][hsub][1] = sw[nt];
        }
    }
    __syncthreads();

    #pragma unroll
    for (int nt = 0; nt < 2; ++nt) {
        float M = red2[0][nt][hsub][0];
        M = fmaxf(M, red2[1][nt][hsub][0]);
        M = fmaxf(M, red2[2][nt][hsub][0]);
        M = fmaxf(M, red2[3][nt][hsub][0]);
        float S = 0.f;
        #pragma unroll
        for (int w2 = 0; w2 < 4; ++w2)
            S += __expf(red2[w2][nt][hsub][0] - M) * red2[w2][nt][hsub][1];
        const float factor = __expf(mw[nt] - M) / S;

        const int h = nt * 4 + hsub;
        float* arow = attn + ((size_t)(h * 512 + b * 4 + j)) * 512;
        const int ua = lane & 3;
        #pragma unroll
        for (int i = 0; i < 2; ++i)
            #pragma unroll
            for (int r = 0; r < 4; ++r) {
                const int trow = w * 32 + i * 16 + ((lane >> 4) & 3) * 4 + r;
                arow[trow * 4 + ua] = ev[nt][i * 4 + r] * factor;
            }
    }
}

// One block per (b, h): out[x=(h,b,j)][c] = sum_u attn[x][u] * v[b,u,h*64+c]
__global__ __launch_bounds__(256) void pv_kernel(const float* __restrict__ v,
                                                 const float* __restrict__ attn,
                                                 float* __restrict__ out) {
    const int bid = blockIdx.x;   // b*8 + h
    const int b = bid >> 3;
    const int h = bid & 7;
    const int tid = threadIdx.x;

    __shared__ float at[4][512];
    __shared__ float red[32][4][68];   // [up][j][c], padded row

    {   // stage attn rows for 4 j values (8 KB, coalesced)
        const int j  = tid >> 6;
        const int u8 = (tid & 63) * 8;
        const float* src = attn + ((size_t)(h * 512 + b * 4 + j)) * 512 + u8;
        *(float4*)&at[j][u8]     = *(const float4*)(src);
        *(float4*)&at[j][u8 + 4] = *(const float4*)(src + 4);
    }
    __syncthreads();

    const int cg = tid & 7;          // channel octet: c8 = cg*8
    const int up = tid >> 3;         // u phase [0,32)
    const int c8 = cg * 8;
    const float* vb = v + (size_t)b * TT * DIN + h * 64 + c8;

    float acc[4][8];
    #pragma unroll
    for (int jj = 0; jj < 4; ++jj)
        #pragma unroll
        for (int ci = 0; ci < 8; ++ci) acc[jj][ci] = 0.f;

    const float* pcur = vb + (size_t)up * DIN;
    float4 r0 = *(const float4*)(pcur);
    float4 r1 = *(const float4*)(pcur + 4);

    for (int it = 0; it < 16; ++it) {
        const int u = it * 32 + up;
        const float4 c0 = r0;
        const float4 c1 = r1;
        if (it < 15) {
            const float* pn = vb + (size_t)(u + 32) * DIN;
            r0 = *(const float4*)(pn);
            r1 = *(const float4*)(pn + 4);
        }
        const float a0 = at[0][u];
        const float a1 = at[1][u];
        const float a2 = at[2][u];
        const float a3 = at[3][u];
        acc[0][0] += a0 * c0.x; acc[0][1] += a0 * c0.y; acc[0][2] += a0 * c0.z; acc[0][3] += a0 * c0.w;
        acc[0][4] += a0 * c1.x; acc[0][5] += a0 * c1.y; acc[0][6] += a0 * c1.z; acc[0][7] += a0 * c1.w;
        acc[1][0] += a1 * c0.x; acc[1][1] += a1 * c0.y; acc[1][2] += a1 * c0.z; acc[1][3] += a1 * c0.w;
        acc[1][4] += a1 * c1.x; acc[1][5] += a1 * c1.y; acc[1][6] += a1 * c1.z; acc[1][7] += a1 * c1.w;
        acc[2][0] += a2 * c0.x; acc[2][1] += a2 * c0.y; acc[2][2] += a2 * c0.z; acc[2][3] += a2 * c0.w;
        acc[2][4] += a2 * c1.x; acc[2][5] += a2 * c1.y; acc[2][6] += a2 * c1.z; acc[2][7] += a2 * c1.w;
        acc[3][0] += a3 * c0.x; acc[3][1] += a3 * c0.y; acc[3][2] += a3 * c0.z; acc[3][3] += a3 * c0.w;
        acc[3][4] += a3 * c1.x; acc[3][5] += a3 * c1.y; acc[3][6] += a3 * c1.z; acc[3][7] += a3 * c1.w;
    }

    #pragma unroll
    for (int jj = 0; jj < 4; ++jj) {
        float4 w0, w1;
        w0.x = acc[jj][0]; w0.y = acc[jj][1]; w0.z = acc[jj][2]; w0.w = acc[jj][3];
        w1.x = acc[jj][4]; w1.y = acc[jj][5]; w1.z = acc[jj][6]; w1.w = acc[jj][7];
        *(float4*)&red[up][jj][c8]     = w0;
        *(float4*)&red[up][jj][c8 + 4] = w1;
    }
    __syncthreads();

    const int jo = tid >> 6;
    const int c  = tid & 63;
    float s = 0.f;
    #pragma unroll
    for (int r2 = 0; r2 < 32; ++r2) s += red[r2][jo][c];
    out[((size_t)(h * 512 + b * 4 + jo)) * 64 + c] = s;
}

extern "C" void kernel_launch(void* const* d_in, const int* in_sizes, int n_in,
                              void* d_out, int out_size, void* d_ws, size_t ws_size,
                              hipStream_t stream) {
    const float* v  = (const float*)d_in[0];
    const float* Q  = (const float*)d_in[1];
    const float* Wk = (const float*)d_in[2];
    const float* bk = (const float*)d_in[3];

    float* out  = (float*)d_out;               // 4096*64
    float* attn = out + 4096 * 64;             // 4096*512

    unsigned short* Pgb = (unsigned short*)d_ws;     // 4*32*512 bf16
    float* qb = (float*)(Pgb + 4 * 32 * 512);        // 128 f32

    pk_kernel<<<128, 512, 0, stream>>>(Q, Wk, bk, Pgb, qb);
    score_kernel<<<512, 256, 0, stream>>>(v, Pgb, qb, attn);
    pv_kernel<<<1024, 256, 0, stream>>>(v, attn, out);
}